// Round 11
// baseline (365.107 us; speedup 1.0000x reference)
//
#include <hip/hip_runtime.h>

// ---------------------------------------------------------------------------
// GCN encoder: out = GCNConv2( relu(GCNConv1(x)) )
// R19: preprocessing rewrite on top of R17 (gathers reverted to RD=8 — R18's
// RD=16 was net-negative). Bucket machinery (hist2/wavescan/ebuf/csrbuild)
// replaced by per-node degree path:
//   D1 zeroconvW: zero deg[] + weight fp16 transpose
//   D2 histdeg:   deg[d]++ global atomics (fire-and-forget)
//   D3 scanoffs:  one-block scan -> offs, dinv, cur
//   D4 scatgemm:  direct scatter csr[atomicAdd(cur[d])]=s  ||  GEMM1 (MFMA)
//   D5 gatherg2:  gather+bias+relu+GEMM2 (RD=8, LDS wL slice)
//   D6 gatherh:   layer-2 gather (RD=8, LDS wL slice)
// Within-node csr order was already atomic-nondeterministic, so direct
// scatter adds no new reordering class; fp32 sum jitter << fp16 floor.
// ---------------------------------------------------------------------------

typedef __attribute__((ext_vector_type(4))) float floatx4;
typedef _Float16 __attribute__((ext_vector_type(8))) half8v;

#define NBLK    256          // blocks for histdeg/scatter

#define AS1(p) ((const __attribute__((address_space(1))) void*)(p))
#define AS3(p) ((__attribute__((address_space(3))) void*)(p))

__device__ __forceinline__ int edge_id(const int* __restrict__ ei, int is64, long long pos) {
    return is64 ? ei[2 * pos] : ei[(int)pos];
}

// per-block is64 detection: int64 node ids (<2^31) => odd dwords all zero.
__device__ __forceinline__ int detect_is64(const int* __restrict__ ei) {
    __shared__ int nz;
    if (threadIdx.x == 0) nz = 0;
    __syncthreads();
    if (threadIdx.x < 256 && ei[2 * threadIdx.x + 1] != 0) atomicOr(&nz, 1);
    __syncthreads();
    return (nz == 0) ? 1 : 0;
}

// variant using caller-provided LDS word (for kernels whose static LDS is full)
__device__ __forceinline__ int detect_is64_buf(const int* __restrict__ ei, int* nzp) {
    if (threadIdx.x == 0) *nzp = 0;
    __syncthreads();
    if (threadIdx.x < 256 && ei[2 * threadIdx.x + 1] != 0) atomicOr(nzp, 1);
    __syncthreads();
    return (*nzp == 0) ? 1 : 0;
}

// ---------------------------------------------------------------------------
// Weight pre-transform helper: W[K][Nc] fp32 -> Wt [Nc][K] fp16
// ---------------------------------------------------------------------------
__device__ __forceinline__ void convW_one(const float* W, _Float16* Wt, int K, int Nc, int idx) {
    if (idx >= K * Nc) return;
    int k = idx / Nc, n = idx % Nc;
    Wt[(long long)n * K + k] = (_Float16)W[idx];
}

// ---- D1: zero deg + weight conversion --------------------------------------
__global__ void __launch_bounds__(256)
zeroconvW_kernel(int* __restrict__ deg, int N,
                 const float* __restrict__ W1, _Float16* __restrict__ W1t,
                 const float* __restrict__ W2, _Float16* __restrict__ W2t) {
    int gtid = blockIdx.x * 256 + threadIdx.x;
    if (gtid < N) deg[gtid] = 0;
    convW_one(W1, W1t, 256, 128, gtid);
    int g2 = gtid - 256 * 128;
    if (g2 >= 0) convW_one(W2, W2t, 128, 64, g2);
}

// ---- D2: per-node in-degree via global atomics ------------------------------
__global__ void __launch_bounds__(256)
histdeg_kernel(const int* __restrict__ ei, int* __restrict__ deg, int E, int chunk) {
    const int is64 = detect_is64(ei);
    const int lo = blockIdx.x * chunk;
    const int hi = min(E, lo + chunk);
    for (int e = lo + threadIdx.x; e < hi; e += 256) {
        int d = edge_id(ei, is64, (long long)E + e);
        atomicAdd(&deg[d], 1);
    }
}

// ---- D3: one-block scan of deg -> offs, dinv, cur ---------------------------
__global__ void __launch_bounds__(1024)
scanoffs_kernel(const int* __restrict__ deg, int* __restrict__ offs,
                float* __restrict__ dinv, int* __restrict__ cur, int N, int E) {
    __shared__ int sm[1024];
    const int t = threadIdx.x;
    const int CH = (N + 1023) / 1024;
    const int b0 = min(t * CH, N);
    const int b1 = min(b0 + CH, N);
    int sum = 0;
    for (int i = b0; i < b1; ++i) sum += deg[i];
    sm[t] = sum;
    __syncthreads();
    int v = sm[t];
    for (int s = 1; s < 1024; s <<= 1) {
        int u = (t >= s) ? sm[t - s] : 0;
        __syncthreads();
        sm[t] += u;
        __syncthreads();
    }
    int run = sm[t] - v;   // exclusive prefix of this thread's chunk
    for (int i = b0; i < b1; ++i) {
        int dg = deg[i];
        offs[i] = run;
        cur[i]  = run;
        dinv[i] = rsqrtf(1.0f + (float)dg);
        run += dg;
    }
    if (t == 0) offs[N] = E;
}

// ---------------------------------------------------------------------------
// GEMM1 body (BM=128, BK=64, async LDS, XOR swizzle) — unchanged from R17.
// ---------------------------------------------------------------------------
__device__ __forceinline__ void gemm1_body(char* smem,
                                           const float* __restrict__ A,
                                           const _Float16* __restrict__ Bt,
                                           _Float16* __restrict__ C, int M, int bid) {
    constexpr int NCOL = 128, K = 256;
    constexpr int NCB = NCOL / 16;
    constexpr int BM = 128, BK = 64;
    constexpr int NC = K / BK;
    constexpr int UNITS = BM * BK / 4;
    float* As = (float*)smem;            // [2][BM*BK]

    const int tid  = threadIdx.x;
    const int wave = tid >> 6;
    const int lane = tid & 63;
    const int n15  = lane & 15;
    const int q    = lane >> 4;
    const int row0 = bid * BM;

    floatx4 acc[2][NCB];
#pragma unroll
    for (int rt = 0; rt < 2; ++rt)
#pragma unroll
        for (int c = 0; c < NCB; ++c) acc[rt][c] = (floatx4){0.f, 0.f, 0.f, 0.f};

    auto stage = [&](int buf, int kc) {
#pragma unroll
        for (int j = 0; j < UNITS / 256; ++j) {
            int g = j * 256 + tid;
            int r = g >> 4;
            int u = (g & 15) ^ (r & 15);
            int gr = row0 + r;
            if (gr >= M) gr = M - 1;
            const float* gp = &A[(long long)gr * K + kc + u * 4];
            float* lp = &As[buf * (BM * BK) + g * 4];
            __builtin_amdgcn_global_load_lds(AS1(gp), AS3(lp), 16, 0, 0);
        }
    };

    stage(0, 0);
    __syncthreads();

#pragma unroll
    for (int c = 0; c < NC; ++c) {
        if (c + 1 < NC) stage((c + 1) & 1, (c + 1) * BK);
        const int buf = c & 1;
#pragma unroll
        for (int ks = 0; ks < 2; ++ks) {
            half8v af[2];
#pragma unroll
            for (int rt = 0; rt < 2; ++rt) {
                const int R = wave * 32 + rt * 16 + n15;
                const int u0 = ks * 8 + q * 2;
                const int p0 = (u0)     ^ (R & 15);
                const int p1 = (u0 + 1) ^ (R & 15);
                float4 f0 = *(const float4*)&As[buf * (BM * BK) + R * BK + p0 * 4];
                float4 f1 = *(const float4*)&As[buf * (BM * BK) + R * BK + p1 * 4];
                af[rt][0] = (_Float16)f0.x; af[rt][1] = (_Float16)f0.y;
                af[rt][2] = (_Float16)f0.z; af[rt][3] = (_Float16)f0.w;
                af[rt][4] = (_Float16)f1.x; af[rt][5] = (_Float16)f1.y;
                af[rt][6] = (_Float16)f1.z; af[rt][7] = (_Float16)f1.w;
            }
#pragma unroll
            for (int cb = 0; cb < NCB; ++cb) {
                const _Float16* bp = &Bt[(long long)(cb * 16 + n15) * K + c * BK + ks * 32 + q * 8];
                half8v bf = *(const half8v*)bp;
                acc[0][cb] = __builtin_amdgcn_mfma_f32_16x16x32_f16(af[0], bf, acc[0][cb], 0, 0, 0);
                acc[1][cb] = __builtin_amdgcn_mfma_f32_16x16x32_f16(af[1], bf, acc[1][cb], 0, 0, 0);
            }
        }
        if (c + 1 < NC) __syncthreads();
    }

#pragma unroll
    for (int rt = 0; rt < 2; ++rt) {
#pragma unroll
        for (int cb = 0; cb < NCB; ++cb) {
            int col = cb * 16 + n15;
#pragma unroll
            for (int r = 0; r < 4; ++r) {
                int gr = row0 + wave * 32 + rt * 16 + q * 4 + r;
                if (gr < M) C[(long long)gr * NCOL + col] = (_Float16)acc[rt][cb][r];
            }
        }
    }
}

// ---- D4: direct scatter (global cursors) || GEMM1 ---------------------------
__global__ void __launch_bounds__(256)
scatgemm_kernel(const int* __restrict__ ei, int* __restrict__ cur, int* __restrict__ csr,
                int E, int chunk,
                const float* __restrict__ A, const _Float16* __restrict__ Bt,
                _Float16* __restrict__ C, int M, int nGemm) {
    __shared__ __align__(16) char smem[65536];
    const int bid = blockIdx.x;
    if (bid < nGemm) {
        gemm1_body(smem, A, Bt, C, M, bid);
    } else {
        const int is64 = detect_is64_buf(ei, (int*)smem);
        const int sb = bid - nGemm;
        const int lo = sb * chunk;
        const int hi = min(E, lo + chunk);
        for (int e = lo + threadIdx.x; e < hi; e += 256) {
            int s = edge_id(ei, is64, e);
            int d = edge_id(ei, is64, (long long)E + e);
            int pos = atomicAdd(&cur[d], 1);
            csr[pos] = s;
        }
    }
}

// ---------------------------------------------------------------------------
// FUSED: layer-1 aggregation (gather + bias + relu) + GEMM2 -> h2 fp16.
// RD=8 rounds, LDS weight slice, 4-wave MFMA tail. (R17 version.)
// ---------------------------------------------------------------------------
__launch_bounds__(256)
__global__ void gatherg2_kernel(const _Float16* __restrict__ h,   // h1 [N][128]
                                const int* __restrict__ csr,
                                const int* __restrict__ offs,
                                const float* __restrict__ dinv,
                                const float* __restrict__ bias,   // b1
                                const _Float16* __restrict__ Bt,  // W2t [64][128]
                                _Float16* __restrict__ C,         // h2 [N][64]
                                int N) {
    constexpr int F = 128;        // in-channels (K of the GEMM)
    constexpr int NCOL = 64;
    constexpr int L = F / 8;      // 16 lanes per node
    constexpr int NPB = 256 / L;  // 16 nodes per block
    constexpr int CAP = 1536;     // staged edges (avg slice ~260)
    __shared__ _Float16 Ash[NPB * F];   // 4 KB
    __shared__ float wL[CAP];           // 6 KB

    const int r  = threadIdx.x / L;     // local row (node) 0..15
    const int l  = threadIdx.x % L;     // unit lane 0..15
    const int c8 = l * 8;
    const int n  = blockIdx.x * NPB + r;

    // ---- weight-slice staging prologue (all threads) ----
    const int n0   = blockIdx.x * NPB;
    const int nend = min(n0 + NPB, N);
    const int lo   = offs[n0];
    const int cntS = min(offs[nend] - lo, CAP);
    for (int i = threadIdx.x; i < cntS; i += 256)
        wL[i] = dinv[csr[lo + i]];
    __syncthreads();

    float acc[8];
    if (n < N) {
        const float di = dinv[n];
        half8v hs = *(const half8v*)&h[(long long)n * F + c8];
        const float sd = di * di;
#pragma unroll
        for (int j = 0; j < 8; ++j) acc[j] = (float)hs[j] * sd;

        const int end = offs[n + 1];
        for (int j = offs[n]; j < end; j += 8) {
            int s[8];
            float ws[8];
            half8v v[8];
#pragma unroll
            for (int u = 0; u < 8; ++u) {
                int jj = j + u;
                s[u] = csr[jj < end ? jj : end - 1];
            }
#pragma unroll
            for (int u = 0; u < 8; ++u) {
                int jj = j + u;
                float w = (jj - lo < CAP) ? wL[jj - lo] : dinv[s[u]];
                ws[u] = (jj < end) ? w * di : 0.f;
            }
#pragma unroll
            for (int u = 0; u < 8; ++u) v[u] = *(const half8v*)&h[(long long)s[u] * F + c8];
#pragma unroll
            for (int u = 0; u < 8; ++u) {
#pragma unroll
                for (int t = 0; t < 8; ++t) acc[t] = fmaf((float)v[u][t], ws[u], acc[t]);
            }
        }
        float4 b0 = *(const float4*)&bias[c8];
        float4 b1v = *(const float4*)&bias[c8 + 4];
        float bb[8] = {b0.x, b0.y, b0.z, b0.w, b1v.x, b1v.y, b1v.z, b1v.w};
#pragma unroll
        for (int t = 0; t < 8; ++t) acc[t] = fmaxf(acc[t] + bb[t], 0.f);
    } else {
#pragma unroll
        for (int t = 0; t < 8; ++t) acc[t] = 0.f;
    }

    // pack fp16 and store to the swizzled LDS tile (16B unit l at l^r)
    half8v hv;
#pragma unroll
    for (int t = 0; t < 8; ++t) hv[t] = (_Float16)acc[t];
    *(half8v*)&Ash[(r * 16 + (l ^ r)) * 8] = hv;
    __syncthreads();

    // MFMA tail on all 4 waves: wave w -> output cols [16w, 16w+16)
    {
        const int lane = threadIdx.x & 63;
        const int wv   = threadIdx.x >> 6;      // cb = wave id
        const int n15  = lane & 15;
        const int q    = lane >> 4;
        floatx4 acc2 = (floatx4){0.f, 0.f, 0.f, 0.f};
#pragma unroll
        for (int kc = 0; kc < 4; ++kc) {
            const int u = (kc * 4 + q) ^ n15;
            half8v af = *(const half8v*)&Ash[(n15 * 16 + u) * 8];
            const _Float16* bp = &Bt[(long long)(wv * 16 + n15) * F + kc * 32 + q * 8];
            half8v bf = *(const half8v*)bp;
            acc2 = __builtin_amdgcn_mfma_f32_16x16x32_f16(af, bf, acc2, 0, 0, 0);
        }
        const int col = wv * 16 + n15;
#pragma unroll
        for (int rr = 0; rr < 4; ++rr) {
            int gr = blockIdx.x * NPB + q * 4 + rr;
            if (gr < N) C[(long long)gr * NCOL + col] = (_Float16)acc2[rr];
        }
    }
}

// ---------------------------------------------------------------------------
// Gather aggregation (layer 2), fp16 h, RD=8 rounds + LDS weight slice.
// ---------------------------------------------------------------------------
template <int F, int RELU>
__launch_bounds__(256)
__global__ void gatherh_kernel(const _Float16* __restrict__ h, const int* __restrict__ csr,
                               const int* __restrict__ offs, const float* __restrict__ dinv,
                               const float* __restrict__ bias, float* __restrict__ out, int N) {
    constexpr int L = F / 8;
    constexpr int NPB = 256 / L;
    constexpr int CAP = 2048;
    __shared__ float wL[CAP];           // 8 KB
    const int n = blockIdx.x * NPB + threadIdx.x / L;
    const int c8 = (threadIdx.x % L) * 8;

    // ---- weight-slice staging prologue (all threads) ----
    const int n0   = blockIdx.x * NPB;
    const int nend = min(n0 + NPB, N);
    const int lo   = offs[n0];
    const int cntS = min(offs[nend] - lo, CAP);
    for (int i = threadIdx.x; i < cntS; i += 256)
        wL[i] = dinv[csr[lo + i]];
    __syncthreads();

    if (n >= N) return;

    const float di = dinv[n];
    half8v hs = *(const half8v*)&h[(long long)n * F + c8];
    float acc[8];
    const float sd = di * di;
#pragma unroll
    for (int j = 0; j < 8; ++j) acc[j] = (float)hs[j] * sd;

    const int end = offs[n + 1];
    for (int j = offs[n]; j < end; j += 8) {
        int s[8];
        float ws[8];
        half8v v[8];
#pragma unroll
        for (int u = 0; u < 8; ++u) {
            int jj = j + u;
            s[u] = csr[jj < end ? jj : end - 1];
        }
#pragma unroll
        for (int u = 0; u < 8; ++u) {
            int jj = j + u;
            float w = (jj - lo < CAP) ? wL[jj - lo] : dinv[s[u]];
            ws[u] = (jj < end) ? w * di : 0.f;
        }
#pragma unroll
        for (int u = 0; u < 8; ++u) v[u] = *(const half8v*)&h[(long long)s[u] * F + c8];
#pragma unroll
        for (int u = 0; u < 8; ++u) {
#pragma unroll
            for (int t = 0; t < 8; ++t) acc[t] = fmaf((float)v[u][t], ws[u], acc[t]);
        }
    }

    float4 b0 = *(const float4*)&bias[c8];
    float4 b1 = *(const float4*)&bias[c8 + 4];
    float bb[8] = {b0.x, b0.y, b0.z, b0.w, b1.x, b1.y, b1.z, b1.w};
#pragma unroll
    for (int t = 0; t < 8; ++t) {
        acc[t] += bb[t];
        if (RELU) acc[t] = fmaxf(acc[t], 0.f);
    }
    float* o = &out[(long long)n * F + c8];
    *(float4*)o       = make_float4(acc[0], acc[1], acc[2], acc[3]);
    *(float4*)(o + 4) = make_float4(acc[4], acc[5], acc[6], acc[7]);
}

extern "C" void kernel_launch(void* const* d_in, const int* in_sizes, int n_in,
                              void* d_out, int out_size, void* d_ws, size_t ws_size,
                              hipStream_t stream) {
    const float* x  = (const float*)d_in[0];
    const int*   ei = (const int*)d_in[1];
    const float* W1 = (const float*)d_in[2];
    const float* b1 = (const float*)d_in[3];
    const float* W2 = (const float*)d_in[4];
    const float* b2 = (const float*)d_in[5];
    float* out = (float*)d_out;

    const int IN_CH = 256, HID = 128, OUT = 64;
    const int N = in_sizes[0] / IN_CH;     // 50000
    const int E = in_sizes[1] / 2;         // 800000
    const int chunk = (E + NBLK - 1) / NBLK;
    const int nGemm = (N + 127) / 128;     // 391 GEMM1 blocks

    char* w = (char*)d_ws;
    size_t off_b = 0;
    auto alloc = [&](size_t bytes) { void* p = w + off_b; off_b = (off_b + bytes + 255) & ~(size_t)255; return p; };
    int*   deg     = (int*)alloc((size_t)N * 4);
    int*   cur     = (int*)alloc((size_t)N * 4);
    int*   offs    = (int*)alloc((size_t)(N + 1) * 4);
    float* dinv    = (float*)alloc((size_t)N * 4);
    int*   csr     = (int*)alloc((size_t)E * 4);
    _Float16* W1t  = (_Float16*)alloc((size_t)IN_CH * HID * 2);
    _Float16* W2t  = (_Float16*)alloc((size_t)HID * OUT * 2);
    _Float16* h1   = (_Float16*)alloc((size_t)N * HID * 2); // fp16 (live through fused kernel)
    _Float16* h2   = (_Float16*)alloc((size_t)N * OUT * 2); // fp16

    // --- 6 dispatches total ------------------------------------------------
    zeroconvW_kernel<<<(N + 255) / 256, 256, 0, stream>>>(deg, N, W1, W1t, W2, W2t);
    histdeg_kernel<<<NBLK, 256, 0, stream>>>(ei, deg, E, chunk);
    scanoffs_kernel<<<1, 1024, 0, stream>>>(deg, offs, dinv, cur, N, E);
    // direct scatter (256 blocks) || GEMM1 (391 blocks)
    scatgemm_kernel<<<nGemm + NBLK, 256, 0, stream>>>(ei, cur, csr, E, chunk,
                                                      x, W1t, h1, N, nGemm);
    // FUSED layer-1 aggregation + GEMM2 -> h2[N,64] fp16
    gatherg2_kernel<<<(N + 15) / 16, 256, 0, stream>>>(h1, csr, offs, dinv, b1, W2t, h2, N);
    // layer-2 aggregation (fp16 gather, fused self-loop + bias) -> out (fp32)
    gatherh_kernel<64, 0><<<(N * 8 + 255) / 256, 256, 0, stream>>>(h2, csr, offs, dinv, b2, out, N);
}

// Round 12
// 194.063 us; speedup vs baseline: 1.8814x; 1.8814x over previous
//
#include <hip/hip_runtime.h>

// ---------------------------------------------------------------------------
// GCN encoder: out = GCNConv2( relu(GCNConv1(x)) )
// R20 = R17 exact revert (best verified: 195.6us). R19's degree-direct
// preprocessing regressed +170us (single-block scanoffs 134us; random 4B
// csr scatter +35us) — bucket-local write streams win. R18's RD=16
// regressed gatherh. Schedule: hist2convW -> wavescan -> scatter2b ->
// (csrbuild || GEMM1) -> gatherg2(+GEMM2) -> gatherh.
// ---------------------------------------------------------------------------

typedef __attribute__((ext_vector_type(4))) float floatx4;
typedef _Float16 __attribute__((ext_vector_type(8))) half8v;

#define BUCK_SH 6
#define BUCK    64           // dsts per bucket
#define NBLK    256          // blocks for hist2/scatter2

#define AS1(p) ((const __attribute__((address_space(1))) void*)(p))
#define AS3(p) ((__attribute__((address_space(3))) void*)(p))

__device__ __forceinline__ int edge_id(const int* __restrict__ ei, int is64, long long pos) {
    return is64 ? ei[2 * pos] : ei[(int)pos];
}

// per-block is64 detection: int64 node ids (<2^31) => odd dwords all zero.
__device__ __forceinline__ int detect_is64(const int* __restrict__ ei) {
    __shared__ int nz;
    if (threadIdx.x == 0) nz = 0;
    __syncthreads();
    if (threadIdx.x < 256 && ei[2 * threadIdx.x + 1] != 0) atomicOr(&nz, 1);
    __syncthreads();
    return (nz == 0) ? 1 : 0;
}

// ---------------------------------------------------------------------------
// Weight pre-transform helper: W[K][Nc] fp32 -> Wt [Nc][K] fp16
// ---------------------------------------------------------------------------
__device__ __forceinline__ void convW_one(const float* W, _Float16* Wt, int K, int Nc, int idx) {
    if (idx >= K * Nc) return;
    int k = idx / Nc, n = idx % Nc;
    Wt[(long long)n * K + k] = (_Float16)W[idx];
}

// ---- fused: per-block bucket histogram + weight conversion -----------------
__global__ void __launch_bounds__(256)
hist2convW_kernel(const int* __restrict__ ei, int* __restrict__ hist2,
                  int E, int NB, int chunk,
                  const float* __restrict__ W1, _Float16* __restrict__ W1t,
                  const float* __restrict__ W2, _Float16* __restrict__ W2t) {
    __shared__ int h[1024];
    const int t = threadIdx.x;
    const int is64 = detect_is64(ei);
    for (int i = t; i < NB; i += 256) h[i] = 0;
    __syncthreads();
    const int lo = blockIdx.x * chunk;
    const int hi = min(E, lo + chunk);
    for (int e = lo + t; e < hi; e += 256) {
        int d = edge_id(ei, is64, (long long)E + e);
        atomicAdd(&h[d >> BUCK_SH], 1);
    }
    __syncthreads();
    for (int i = t; i < NB; i += 256) hist2[(long long)blockIdx.x * NB + i] = h[i];
    // weight conversion: 65536 grid threads cover 32768 + 8192 elements
    {
        int gtid = blockIdx.x * 256 + t;
        convW_one(W1, W1t, 256, 128, gtid);
        int g2 = gtid - 256 * 128;
        if (g2 >= 0) convW_one(W2, W2t, 128, 64, g2);
    }
}

// ---- wavescan: ONE WAVE PER BUCKET, shuffle-scan over the 256 block counts -
__global__ void __launch_bounds__(256)
wavescan_kernel(const int* __restrict__ hist2, int* __restrict__ start2t,
                int* __restrict__ colsum, int NB) {
    const int wid  = (blockIdx.x * 256 + threadIdx.x) >> 6;   // bucket id
    const int lane = threadIdx.x & 63;
    if (wid >= NB) return;
    int carry = 0;
    for (int c = 0; c < NBLK; c += 64) {
        int v = hist2[(long long)(c + lane) * NB + wid];
        int incl = v;
#pragma unroll
        for (int s = 1; s < 64; s <<= 1) {
            int u = __shfl_up(incl, s, 64);
            if (lane >= s) incl += u;
        }
        start2t[(long long)wid * NBLK + c + lane] = carry + incl - v;   // exclusive
        carry += __shfl(incl, 63, 64);
    }
    if (lane == 0) colsum[wid] = carry;
}

// ---- scatter2b: scatter + internal colsum scan (replaces basescan) ---------
__global__ void __launch_bounds__(256)
scatter2b_kernel(const int* __restrict__ ei, const int* __restrict__ colsum,
                 const int* __restrict__ start2t, unsigned* __restrict__ ebuf,
                 int* __restrict__ bbase_g, int E, int NB, int chunk) {
    __shared__ int tsum[256];
    __shared__ int bb[1024];
    __shared__ int hcur[1024];
    const int t = threadIdx.x;
    const int is64 = detect_is64(ei);

    // two-level exclusive scan of colsum (padded to 1024 with zeros)
    int c[4];
#pragma unroll
    for (int k = 0; k < 4; ++k) {
        int i = t * 4 + k;
        c[k] = (i < NB) ? colsum[i] : 0;
    }
    tsum[t] = c[0] + c[1] + c[2] + c[3];
    __syncthreads();
    int v = tsum[t];
    for (int s = 1; s < 256; s <<= 1) {
        int u = (t >= s) ? tsum[t - s] : 0;
        __syncthreads();
        tsum[t] += u;
        __syncthreads();
    }
    int run = tsum[t] - v;   // exclusive prefix of this thread's 4-chunk
#pragma unroll
    for (int k = 0; k < 4; ++k) {
        bb[t * 4 + k] = run;
        run += c[k];
    }
    __syncthreads();

    // publish bbase once (block 0) for csrbuild
    if (blockIdx.x == 0) {
        for (int i = t; i < NB; i += 256) bbase_g[i] = bb[i];
        if (t == 0) bbase_g[NB] = E;
    }

    for (int i = t; i < NB; i += 256)
        hcur[i] = bb[i] + start2t[(long long)i * NBLK + blockIdx.x];
    __syncthreads();

    const int lo = blockIdx.x * chunk;
    const int hi = min(E, lo + chunk);
    for (int e = lo + t; e < hi; e += 256) {
        int s = edge_id(ei, is64, e);
        int d = edge_id(ei, is64, (long long)E + e);
        int pos = atomicAdd(&hcur[d >> BUCK_SH], 1);
        ebuf[pos] = (unsigned)s | ((unsigned)(d & (BUCK - 1)) << 26);
    }
}

// ---------------------------------------------------------------------------
// FUSED dispatch: GEMM1 blocks [0, nGemm) + csrbuild blocks [nGemm, nGemm+NB).
// ---------------------------------------------------------------------------
__device__ __forceinline__ void gemm1_body(char* smem,
                                           const float* __restrict__ A,
                                           const _Float16* __restrict__ Bt,
                                           _Float16* __restrict__ C, int M, int bid) {
    constexpr int NCOL = 128, K = 256;
    constexpr int NCB = NCOL / 16;
    constexpr int BM = 128, BK = 64;
    constexpr int NC = K / BK;
    constexpr int UNITS = BM * BK / 4;
    float* As = (float*)smem;            // [2][BM*BK]

    const int tid  = threadIdx.x;
    const int wave = tid >> 6;
    const int lane = tid & 63;
    const int n15  = lane & 15;
    const int q    = lane >> 4;
    const int row0 = bid * BM;

    floatx4 acc[2][NCB];
#pragma unroll
    for (int rt = 0; rt < 2; ++rt)
#pragma unroll
        for (int c = 0; c < NCB; ++c) acc[rt][c] = (floatx4){0.f, 0.f, 0.f, 0.f};

    auto stage = [&](int buf, int kc) {
#pragma unroll
        for (int j = 0; j < UNITS / 256; ++j) {
            int g = j * 256 + tid;
            int r = g >> 4;
            int u = (g & 15) ^ (r & 15);
            int gr = row0 + r;
            if (gr >= M) gr = M - 1;
            const float* gp = &A[(long long)gr * K + kc + u * 4];
            float* lp = &As[buf * (BM * BK) + g * 4];
            __builtin_amdgcn_global_load_lds(AS1(gp), AS3(lp), 16, 0, 0);
        }
    };

    stage(0, 0);
    __syncthreads();

#pragma unroll
    for (int c = 0; c < NC; ++c) {
        if (c + 1 < NC) stage((c + 1) & 1, (c + 1) * BK);
        const int buf = c & 1;
#pragma unroll
        for (int ks = 0; ks < 2; ++ks) {
            half8v af[2];
#pragma unroll
            for (int rt = 0; rt < 2; ++rt) {
                const int R = wave * 32 + rt * 16 + n15;
                const int u0 = ks * 8 + q * 2;
                const int p0 = (u0)     ^ (R & 15);
                const int p1 = (u0 + 1) ^ (R & 15);
                float4 f0 = *(const float4*)&As[buf * (BM * BK) + R * BK + p0 * 4];
                float4 f1 = *(const float4*)&As[buf * (BM * BK) + R * BK + p1 * 4];
                af[rt][0] = (_Float16)f0.x; af[rt][1] = (_Float16)f0.y;
                af[rt][2] = (_Float16)f0.z; af[rt][3] = (_Float16)f0.w;
                af[rt][4] = (_Float16)f1.x; af[rt][5] = (_Float16)f1.y;
                af[rt][6] = (_Float16)f1.z; af[rt][7] = (_Float16)f1.w;
            }
#pragma unroll
            for (int cb = 0; cb < NCB; ++cb) {
                const _Float16* bp = &Bt[(long long)(cb * 16 + n15) * K + c * BK + ks * 32 + q * 8];
                half8v bf = *(const half8v*)bp;
                acc[0][cb] = __builtin_amdgcn_mfma_f32_16x16x32_f16(af[0], bf, acc[0][cb], 0, 0, 0);
                acc[1][cb] = __builtin_amdgcn_mfma_f32_16x16x32_f16(af[1], bf, acc[1][cb], 0, 0, 0);
            }
        }
        if (c + 1 < NC) __syncthreads();
    }

#pragma unroll
    for (int rt = 0; rt < 2; ++rt) {
#pragma unroll
        for (int cb = 0; cb < NCB; ++cb) {
            int col = cb * 16 + n15;
#pragma unroll
            for (int r = 0; r < 4; ++r) {
                int gr = row0 + wave * 32 + rt * 16 + q * 4 + r;
                if (gr < M) C[(long long)gr * NCOL + col] = (_Float16)acc[rt][cb][r];
            }
        }
    }
}

__device__ __forceinline__ void csrbuild_body(char* smem,
                                              const unsigned* __restrict__ ebuf,
                                              const int* __restrict__ bbase,
                                              int* __restrict__ offs, float* __restrict__ dinv,
                                              int* __restrict__ csr, int N, int NB, int E, int b) {
    int* cnt = (int*)smem;
    int* exc = cnt + BUCK;
    int* cur = exc + BUCK;
    const int t = threadIdx.x;
    if (t < BUCK) { cnt[t] = 0; cur[t] = 0; }
    __syncthreads();
    const int lo = bbase[b], hi = bbase[b + 1];
    for (int i = lo + t; i < hi; i += 256)
        atomicAdd(&cnt[ebuf[i] >> 26], 1);
    __syncthreads();
    if (t == 0) {
        int run = 0;
        for (int l = 0; l < BUCK; ++l) { exc[l] = run; run += cnt[l]; }
    }
    __syncthreads();
    if (t < BUCK) {
        int n = b * BUCK + t;
        if (n < N) {
            offs[n] = lo + exc[t];
            dinv[n] = rsqrtf(1.0f + (float)cnt[t]);
        }
    }
    if (b == NB - 1 && t == 0) offs[N] = E;
    for (int i = lo + t; i < hi; i += 256) {
        unsigned e = ebuf[i];
        int l = e >> 26;
        int p = lo + exc[l] + atomicAdd(&cur[l], 1);
        csr[p] = (int)(e & 0x03FFFFFFu);
    }
}

__global__ void __launch_bounds__(256)
csrgemm_kernel(const unsigned* __restrict__ ebuf, const int* __restrict__ bbase,
               int* __restrict__ offs, float* __restrict__ dinv, int* __restrict__ csr,
               int N, int NB, int E,
               const float* __restrict__ A, const _Float16* __restrict__ Bt,
               _Float16* __restrict__ C, int M, int nGemm) {
    __shared__ __align__(16) char smem[65536];
    const int bid = blockIdx.x;
    if (bid < nGemm) {
        gemm1_body(smem, A, Bt, C, M, bid);
    } else {
        csrbuild_body(smem, ebuf, bbase, offs, dinv, csr, N, NB, E, bid - nGemm);
    }
}

// ---------------------------------------------------------------------------
// FUSED: layer-1 aggregation (gather + bias + relu) + GEMM2 -> h2 fp16.
// LDS weight slice wL (plain loads), RD=8 loop, 4-wave MFMA tail.
// ---------------------------------------------------------------------------
__launch_bounds__(256)
__global__ void gatherg2_kernel(const _Float16* __restrict__ h,   // h1 [N][128]
                                const int* __restrict__ csr,
                                const int* __restrict__ offs,
                                const float* __restrict__ dinv,
                                const float* __restrict__ bias,   // b1
                                const _Float16* __restrict__ Bt,  // W2t [64][128]
                                _Float16* __restrict__ C,         // h2 [N][64]
                                int N) {
    constexpr int F = 128;        // in-channels (K of the GEMM)
    constexpr int NCOL = 64;
    constexpr int L = F / 8;      // 16 lanes per node
    constexpr int NPB = 256 / L;  // 16 nodes per block
    constexpr int CAP = 1536;     // staged edges (avg slice ~260)
    __shared__ _Float16 Ash[NPB * F];   // 4 KB
    __shared__ float wL[CAP];           // 6 KB

    const int r  = threadIdx.x / L;     // local row (node) 0..15
    const int l  = threadIdx.x % L;     // unit lane 0..15
    const int c8 = l * 8;
    const int n  = blockIdx.x * NPB + r;

    // ---- weight-slice staging prologue (all threads) ----
    const int n0   = blockIdx.x * NPB;
    const int nend = min(n0 + NPB, N);
    const int lo   = offs[n0];
    const int cntS = min(offs[nend] - lo, CAP);
    for (int i = threadIdx.x; i < cntS; i += 256)
        wL[i] = dinv[csr[lo + i]];
    __syncthreads();

    float acc[8];
    if (n < N) {
        const float di = dinv[n];
        half8v hs = *(const half8v*)&h[(long long)n * F + c8];
        const float sd = di * di;
#pragma unroll
        for (int j = 0; j < 8; ++j) acc[j] = (float)hs[j] * sd;

        const int end = offs[n + 1];
        for (int j = offs[n]; j < end; j += 8) {
            int s[8];
            float ws[8];
            half8v v[8];
#pragma unroll
            for (int u = 0; u < 8; ++u) {
                int jj = j + u;
                s[u] = csr[jj < end ? jj : end - 1];
            }
#pragma unroll
            for (int u = 0; u < 8; ++u) {
                int jj = j + u;
                float w = (jj - lo < CAP) ? wL[jj - lo] : dinv[s[u]];
                ws[u] = (jj < end) ? w * di : 0.f;
            }
#pragma unroll
            for (int u = 0; u < 8; ++u) v[u] = *(const half8v*)&h[(long long)s[u] * F + c8];
#pragma unroll
            for (int u = 0; u < 8; ++u) {
#pragma unroll
                for (int t = 0; t < 8; ++t) acc[t] = fmaf((float)v[u][t], ws[u], acc[t]);
            }
        }
        float4 b0 = *(const float4*)&bias[c8];
        float4 b1v = *(const float4*)&bias[c8 + 4];
        float bb[8] = {b0.x, b0.y, b0.z, b0.w, b1v.x, b1v.y, b1v.z, b1v.w};
#pragma unroll
        for (int t = 0; t < 8; ++t) acc[t] = fmaxf(acc[t] + bb[t], 0.f);
    } else {
#pragma unroll
        for (int t = 0; t < 8; ++t) acc[t] = 0.f;
    }

    // pack fp16 and store to the swizzled LDS tile (16B unit l at l^r)
    half8v hv;
#pragma unroll
    for (int t = 0; t < 8; ++t) hv[t] = (_Float16)acc[t];
    *(half8v*)&Ash[(r * 16 + (l ^ r)) * 8] = hv;
    __syncthreads();

    // MFMA tail on all 4 waves: wave w -> output cols [16w, 16w+16)
    {
        const int lane = threadIdx.x & 63;
        const int wv   = threadIdx.x >> 6;      // cb = wave id
        const int n15  = lane & 15;
        const int q    = lane >> 4;
        floatx4 acc2 = (floatx4){0.f, 0.f, 0.f, 0.f};
#pragma unroll
        for (int kc = 0; kc < 4; ++kc) {
            const int u = (kc * 4 + q) ^ n15;
            half8v af = *(const half8v*)&Ash[(n15 * 16 + u) * 8];
            const _Float16* bp = &Bt[(long long)(wv * 16 + n15) * F + kc * 32 + q * 8];
            half8v bf = *(const half8v*)bp;
            acc2 = __builtin_amdgcn_mfma_f32_16x16x32_f16(af, bf, acc2, 0, 0, 0);
        }
        const int col = wv * 16 + n15;
#pragma unroll
        for (int rr = 0; rr < 4; ++rr) {
            int gr = blockIdx.x * NPB + q * 4 + rr;
            if (gr < N) C[(long long)gr * NCOL + col] = (_Float16)acc2[rr];
        }
    }
}

// ---------------------------------------------------------------------------
// Gather aggregation (layer 2), fp16 h, csr prefetch + LDS weight slice.
// ---------------------------------------------------------------------------
template <int F, int RELU>
__launch_bounds__(256)
__global__ void gatherh_kernel(const _Float16* __restrict__ h, const int* __restrict__ csr,
                               const int* __restrict__ offs, const float* __restrict__ dinv,
                               const float* __restrict__ bias, float* __restrict__ out, int N) {
    constexpr int L = F / 8;
    constexpr int NPB = 256 / L;
    constexpr int CAP = 2048;
    __shared__ float wL[CAP];           // 8 KB
    const int n = blockIdx.x * NPB + threadIdx.x / L;
    const int c8 = (threadIdx.x % L) * 8;

    // ---- weight-slice staging prologue (all threads) ----
    const int n0   = blockIdx.x * NPB;
    const int nend = min(n0 + NPB, N);
    const int lo   = offs[n0];
    const int cntS = min(offs[nend] - lo, CAP);
    for (int i = threadIdx.x; i < cntS; i += 256)
        wL[i] = dinv[csr[lo + i]];
    __syncthreads();

    if (n >= N) return;

    const float di = dinv[n];
    half8v hs = *(const half8v*)&h[(long long)n * F + c8];
    float acc[8];
    const float sd = di * di;
#pragma unroll
    for (int j = 0; j < 8; ++j) acc[j] = (float)hs[j] * sd;

    const int beg = offs[n], end = offs[n + 1];
    int s[8];
    if (beg < end) {
#pragma unroll
        for (int u = 0; u < 8; ++u) {
            int jj = beg + u;
            s[u] = csr[jj < end ? jj : end - 1];
        }
    }
    for (int j = beg; j < end; j += 8) {
        int sn[8];
        const int jn = j + 8;
#pragma unroll
        for (int u = 0; u < 8; ++u) {
            int jj = jn + u;
            sn[u] = csr[jj < end ? jj : end - 1];
        }
        float ws[8];
        half8v v[8];
#pragma unroll
        for (int u = 0; u < 8; ++u) {
            int jj = j + u;
            float w = (jj - lo < CAP) ? wL[jj - lo] : dinv[s[u]];
            ws[u] = (jj < end) ? w * di : 0.f;
        }
#pragma unroll
        for (int u = 0; u < 8; ++u) v[u] = *(const half8v*)&h[(long long)s[u] * F + c8];
#pragma unroll
        for (int u = 0; u < 8; ++u) {
#pragma unroll
            for (int t = 0; t < 8; ++t) acc[t] = fmaf((float)v[u][t], ws[u], acc[t]);
        }
#pragma unroll
        for (int u = 0; u < 8; ++u) s[u] = sn[u];
    }

    float4 b0 = *(const float4*)&bias[c8];
    float4 b1 = *(const float4*)&bias[c8 + 4];
    float bb[8] = {b0.x, b0.y, b0.z, b0.w, b1.x, b1.y, b1.z, b1.w};
#pragma unroll
    for (int t = 0; t < 8; ++t) {
        acc[t] += bb[t];
        if (RELU) acc[t] = fmaxf(acc[t], 0.f);
    }
    float* o = &out[(long long)n * F + c8];
    *(float4*)o       = make_float4(acc[0], acc[1], acc[2], acc[3]);
    *(float4*)(o + 4) = make_float4(acc[4], acc[5], acc[6], acc[7]);
}

extern "C" void kernel_launch(void* const* d_in, const int* in_sizes, int n_in,
                              void* d_out, int out_size, void* d_ws, size_t ws_size,
                              hipStream_t stream) {
    const float* x  = (const float*)d_in[0];
    const int*   ei = (const int*)d_in[1];
    const float* W1 = (const float*)d_in[2];
    const float* b1 = (const float*)d_in[3];
    const float* W2 = (const float*)d_in[4];
    const float* b2 = (const float*)d_in[5];
    float* out = (float*)d_out;

    const int IN_CH = 256, HID = 128, OUT = 64;
    const int N = in_sizes[0] / IN_CH;     // 50000
    const int E = in_sizes[1] / 2;         // 800000
    const int NB = (N + BUCK - 1) / BUCK;  // 782 buckets (< 1024)
    const int chunk = (E + NBLK - 1) / NBLK;
    const int nGemm = (N + 127) / 128;     // 391 GEMM1 blocks

    char* w = (char*)d_ws;
    size_t off_b = 0;
    auto alloc = [&](size_t bytes) { void* p = w + off_b; off_b = (off_b + bytes + 255) & ~(size_t)255; return p; };
    int*   hist2   = (int*)alloc((size_t)NBLK * NB * 4);
    int*   start2t = (int*)alloc((size_t)NB * NBLK * 4);
    int*   colsum  = (int*)alloc((size_t)NB * 4);
    int*   bbase   = (int*)alloc((size_t)(NB + 1) * 4);
    int*   offs    = (int*)alloc((size_t)(N + 1) * 4);
    float* dinv    = (float*)alloc((size_t)N * 4);
    unsigned* ebuf = (unsigned*)alloc((size_t)E * 4);
    int*   csr     = (int*)alloc((size_t)E * 4);
    _Float16* W1t  = (_Float16*)alloc((size_t)IN_CH * HID * 2);
    _Float16* W2t  = (_Float16*)alloc((size_t)HID * OUT * 2);
    _Float16* h1   = (_Float16*)alloc((size_t)N * HID * 2); // fp16 (live through fused kernel)
    _Float16* h2   = (_Float16*)alloc((size_t)N * OUT * 2); // fp16

    // --- 6 dispatches total ------------------------------------------------
    hist2convW_kernel<<<NBLK, 256, 0, stream>>>(ei, hist2, E, NB, chunk,
                                                W1, W1t, W2, W2t);
    wavescan_kernel<<<(NB * 64 + 255) / 256, 256, 0, stream>>>(hist2, start2t, colsum, NB);
    scatter2b_kernel<<<NBLK, 256, 0, stream>>>(ei, colsum, start2t, ebuf, bbase, E, NB, chunk);
    // csrbuild (782 blocks) || GEMM1 (391 blocks) — independent roles
    csrgemm_kernel<<<nGemm + NB, 256, 0, stream>>>(ebuf, bbase, offs, dinv, csr,
                                                   N, NB, E, x, W1t, h1, N, nGemm);
    // FUSED layer-1 aggregation + GEMM2 -> h2[N,64] fp16
    gatherg2_kernel<<<(N + 15) / 16, 256, 0, stream>>>(h1, csr, offs, dinv, b1, W2t, h2, N);
    // layer-2 aggregation (fp16 gather, fused self-loop + bias) -> out (fp32)
    gatherh_kernel<64, 0><<<(N * 8 + 255) / 256, 256, 0, stream>>>(h2, csr, offs, dinv, b2, out, N);
}